// Round 3
// baseline (106.909 us; speedup 1.0000x reference)
//
#include <hip/hip_runtime.h>
#include <cstdint>
#include <cstddef>

// MemristorDense R14: DISCRIMINATING PROBE round.
// R11/R12/R13 (inline vs table vs occupancy-doubled) all land 88.9-93.3 us,
// deltas tracking kernel COUNT not content. Two hypotheses fit: (a) harness
// fill floor + kernels ~5-10us, (b) k_main ~40us from an unidentified
// invariant binder. This round: exact R11 structure (proven best, bit-exact
// output) + ONE duplicate k_main dispatch writing to a dummy ws region.
// dur_us - 88.9 measures k_main's true cost directly.

#define B128 128
#define NIN  1024
#define NI   1025
#define NO   512
#define NJ   1024
#define GMIN 1.0e-5f
#define GSPAN (1.0e-3f - 1.0e-5f)
#define ZCH  8      // K-chunks over [0,1024)
#define CHUNK 128

__device__ __forceinline__ float flog2(float x) { return __builtin_amdgcn_logf(x); }
__device__ __forceinline__ float fexp2(float x) { return __builtin_amdgcn_exp2f(x); }

// Kernel 1 (grid 256 x 1024): zero out, LT[i][b]=1+log2(x[b][i]), block max -> bmax[256].
__global__ __launch_bounds__(1024) void k_prep(
    const float* __restrict__ x,
    const float* __restrict__ wp, const float* __restrict__ wn,
    const float* __restrict__ bp, const float* __restrict__ bn,
    float* __restrict__ LT, float* __restrict__ bmax, float* __restrict__ out)
{
    const int tid = blockIdx.x * 1024 + threadIdx.x;   // [0, 262144)

    if (tid < B128 * NO) out[tid] = 0.0f;

    if (tid < NI * B128) {
        int i = tid >> 7, b = tid & 127;
        float xv = (i < NIN) ? x[b * NIN + i] : 1.0f;
        LT[tid] = 1.0f + flog2(xv);                 // log2(2x); x=0 -> -inf (correct)
    }

    // NIN*NO = 524288 = 2 * 262144 exactly
    float m = fmaxf(fmaxf(__builtin_fabsf(wp[tid]), __builtin_fabsf(wn[tid])),
                    fmaxf(__builtin_fabsf(wp[tid + 262144]), __builtin_fabsf(wn[tid + 262144])));
    if (tid < NO) m = fmaxf(m, fmaxf(__builtin_fabsf(bp[tid]), __builtin_fabsf(bn[tid])));

    __shared__ float red[16];
    #pragma unroll
    for (int off = 32; off > 0; off >>= 1) m = fmaxf(m, __shfl_down(m, off, 64));
    if ((threadIdx.x & 63) == 0) red[threadIdx.x >> 6] = m;
    __syncthreads();
    if (threadIdx.x < 16) {
        m = red[threadIdx.x];
        #pragma unroll
        for (int off = 8; off > 0; off >>= 1) m = fmaxf(m, __shfl_down(m, off, 16));
        if (threadIdx.x == 0) bmax[blockIdx.x] = m;
    }
}

// Kernel 2: grid (8 o-tiles, 8 b-tiles, 8 K-chunks) x 512 threads (8 waves).
// Identical to R11's proven k_main. Wave s handles i = z*128 + s + 8k,
// k in [0,16). 16 batches/wave; per step: 4 log2 + 32 exp2. LDS reduce
// across 8 waves, bias (i=1024, pure mul) added by z==0 blocks, atomicAdd.
__global__ __launch_bounds__(512) void k_main(
    const float* __restrict__ nd,
    const float* __restrict__ wp, const float* __restrict__ wn,
    const float* __restrict__ bp, const float* __restrict__ bn,
    const float* __restrict__ LT, const float* __restrict__ bmax,
    float* __restrict__ out)
{
    const int lane = threadIdx.x & 63;
    const int s    = threadIdx.x >> 6;      // wave id [0,8)
    const int o    = (blockIdx.x << 6) + lane;
    const int b0   = blockIdx.y << 4;       // 16 batches per block

    // reduce 256 per-block maxima (redundant per wave; L2-hot)
    float m = fmaxf(fmaxf(bmax[lane], bmax[lane + 64]),
                    fmaxf(bmax[lane + 128], bmax[lane + 192]));
    #pragma unroll
    for (int off = 32; off > 0; off >>= 1) m = fmaxf(m, __shfl_down(m, off, 64));
    const float maxw = __shfl(m, 0, 64);
    const float kG = GSPAN / maxw;
    const float C  = 0.5f * maxw / GSPAN;

    const int i0 = blockIdx.z * CHUNK + s;   // this wave's first i

    const float* pnd = nd + (size_t)i0 * NJ + 2 * o;
    const float* pwp = wp + (size_t)i0 * NO + o;
    const float* pwn = wn + (size_t)i0 * NO + o;
    const float* pL  = LT + (size_t)i0 * B128 + b0;

    float accp[16], accn[16];
    #pragma unroll
    for (int k = 0; k < 16; ++k) { accp[k] = 0.0f; accn[k] = 0.0f; }

    // prologue loads for k=0
    float2 nv = *(const float2*)pnd;
    float wvp = *pwp;
    float wvn = *pwn;
    float4 La = *(const float4*)(pL);
    float4 Lb = *(const float4*)(pL + 4);
    float4 Lc = *(const float4*)(pL + 8);
    float4 Ld = *(const float4*)(pL + 12);

    #pragma unroll 3
    for (int k = 0; k < 15; ++k) {
        pnd += 8 * NJ; pwp += 8 * NO; pwn += 8 * NO; pL += 8 * B128;
        float2 nv_n = *(const float2*)pnd;
        float wp_n = *pwp;
        float wn_n = *pwn;
        float4 Lan = *(const float4*)(pL);
        float4 Lbn = *(const float4*)(pL + 4);
        float4 Lcn = *(const float4*)(pL + 8);
        float4 Ldn = *(const float4*)(pL + 12);

        const float Ep = flog2(nv.x);
        const float En = flog2(nv.y);
        const float Wp = flog2(__builtin_fmaf(kG, __builtin_fabsf(wvp), GMIN));
        const float Wn = flog2(__builtin_fmaf(kG, __builtin_fabsf(wvn), GMIN));

        const float Lv[16] = {La.x, La.y, La.z, La.w, Lb.x, Lb.y, Lb.z, Lb.w,
                              Lc.x, Lc.y, Lc.z, Lc.w, Ld.x, Ld.y, Ld.z, Ld.w};
        #pragma unroll
        for (int j = 0; j < 16; ++j) {
            accp[j] += fexp2(__builtin_fmaf(Ep, Lv[j], Wp));
            accn[j] += fexp2(__builtin_fmaf(En, Lv[j], Wn));
        }

        nv = nv_n; wvp = wp_n; wvn = wn_n;
        La = Lan; Lb = Lbn; Lc = Lcn; Ld = Ldn;
    }

    // last step (k=15), no prefetch
    {
        const float Ep = flog2(nv.x);
        const float En = flog2(nv.y);
        const float Wp = flog2(__builtin_fmaf(kG, __builtin_fabsf(wvp), GMIN));
        const float Wn = flog2(__builtin_fmaf(kG, __builtin_fabsf(wvn), GMIN));
        const float Lv[16] = {La.x, La.y, La.z, La.w, Lb.x, Lb.y, Lb.z, Lb.w,
                              Lc.x, Lc.y, Lc.z, Lc.w, Ld.x, Ld.y, Ld.z, Ld.w};
        #pragma unroll
        for (int j = 0; j < 16; ++j) {
            accp[j] += fexp2(__builtin_fmaf(Ep, Lv[j], Wp));
            accn[j] += fexp2(__builtin_fmaf(En, Lv[j], Wn));
        }
    }

    // LDS reduce across the 8 waves. Row stride 33 floats -> conflict-free.
    __shared__ float lds[8 * 64 * 33];   // 67584 B
    {
        const int base = (s * 64 + lane) * 33;
        #pragma unroll
        for (int j = 0; j < 16; ++j) { lds[base + j] = accp[j]; lds[base + 16 + j] = accn[j]; }
    }
    __syncthreads();

    // bias row (i=1024): L=1 -> term = exp2(E+W) = n * g. Batch-independent;
    // added once per output by the z==0 blocks. Pure multiplies, no exp2.
    float bias = 0.0f;
    if (blockIdx.z == 0) {
        const float2 nb = *(const float2*)(nd + (size_t)NIN * NJ + 2 * o);
        const float gp = __builtin_fmaf(kG, __builtin_fabsf(bp[o]), GMIN);
        const float gn = __builtin_fmaf(kG, __builtin_fabsf(bn[o]), GMIN);
        bias = nb.x * gp - nb.y * gn;
    }

    {
        const int l = threadIdx.x & 63;
        #pragma unroll
        for (int r = 0; r < 2; ++r) {
            const int bb = (threadIdx.x >> 6) + (r << 3);   // [0,16)
            float sum = bias;
            #pragma unroll
            for (int w = 0; w < 8; ++w) {
                const int base = (w * 64 + l) * 33;
                sum += lds[base + bb] - lds[base + 16 + bb];
            }
            unsafeAtomicAdd(out + (size_t)(b0 + bb) * NO + (blockIdx.x << 6) + l, C * sum);
        }
    }
}

extern "C" void kernel_launch(void* const* d_in, const int* in_sizes, int n_in,
                              void* d_out, int out_size, void* d_ws, size_t ws_size,
                              hipStream_t stream)
{
    const float* x  = (const float*)d_in[0];
    const float* wp = (const float*)d_in[1];
    const float* wn = (const float*)d_in[2];
    const float* bp = (const float*)d_in[3];
    const float* bn = (const float*)d_in[4];
    const float* nd = (const float*)d_in[5];
    float* out = (float*)d_out;

    unsigned char* ws = (unsigned char*)d_ws;
    float* bmax = (float*)ws;                 // 256 floats
    float* LT   = (float*)(ws + 4096);        // 1025*128*4 = 524800 B
    // PROBE: dummy output region deep inside ws (needs 256 KB; ws is 256 MiB).
    float* out_probe = (float*)(ws + (16u << 20));

    k_prep<<<256, 1024, 0, stream>>>(x, wp, wn, bp, bn, LT, bmax, out);
    // Real dispatch (bit-identical to R11's proven kernel):
    k_main<<<dim3(8, 8, ZCH), 512, 0, stream>>>(nd, wp, wn, bp, bn, LT, bmax, out);
    // Probe dispatch: identical work, writes only into scratch ws.
    // dur_us minus the R11 baseline (88.9) measures k_main's true duration.
    k_main<<<dim3(8, 8, ZCH), 512, 0, stream>>>(nd, wp, wn, bp, bn, LT, bmax, out_probe);
}